// Round 2
// baseline (7693.496 us; speedup 1.0000x reference)
//
#include <hip/hip_runtime.h>

// ---------------------------------------------------------------------------
// RITS recurrent scan, model-parallel persistent kernel.
// 8 groups x 64 batch rows; each group = 32 blocks (1 per CU).
// Block (g, r): owns H-slice [16r,16r+16) (LSTM gates + state + W_dh rows) and
// F-tile ft = r&7 (x_h/x_c/z_h/alpha/c_h/c_c chain), replicated 4x (rep = r>>3).
// All weights live in VGPRs/LDS (loaded once). Per-step activation exchange
// between the 32 blocks goes through the coherent memory-side LLC using
// PER-INSTRUCTION agent-scope coherence (sc1 stores/loads). No cache-wide
// fences ever execute, so weights and [B,T,F] inputs stay in L1/L2.
//
// Exchange layout: CHUNKED ROW-MAJOR bf16 [chunk = col/16][row 0..63][16 cols].
// Producer stores are dense (4x32B segments per store instruction, no 2B
// scatter); consumer MFMA A-frag gathers read two contiguous 512B regions per
// instruction. Barrier: per-block arrival FLAG (plain sc1 store of monotonic
// seq) + one 32-lane poll load, replacing 32 serialized atomic RMWs.
// Exchange buffers double-buffered by t-parity so 3 barriers/step suffice.
// ---------------------------------------------------------------------------

using short8 = __attribute__((ext_vector_type(8))) short;
using f32x4  = __attribute__((ext_vector_type(4))) float;
using fvec4  = __attribute__((ext_vector_type(4))) float;
using ivec4  = __attribute__((ext_vector_type(4))) int;
using uvec4  = __attribute__((ext_vector_type(4))) unsigned int;

#define LOG2E 1.4426950408889634f

union U8 {
  unsigned u[4];
  unsigned long long q[2];
  short8 s;
  uvec4 v;
};

static __device__ __forceinline__ unsigned short f2bf(float f){
  unsigned u = __builtin_bit_cast(unsigned, f);
  u += 0x7fffu + ((u>>16)&1u);
  return (unsigned short)(u>>16);
}
static __device__ __forceinline__ float fexp2(float x){ return __builtin_amdgcn_exp2f(x); }
static __device__ __forceinline__ float frcp(float x){ return __builtin_amdgcn_rcpf(x); }
static __device__ __forceinline__ float sigm(float x){ return frcp(1.f + fexp2(-LOG2E*x)); }
static __device__ __forceinline__ float tanh_(float x){
  x = fminf(fmaxf(x,-10.f),10.f);
  float e = fexp2(2.f*LOG2E*x);
  return (e-1.f)*frcp(e+1.f);
}
static __device__ __forceinline__ f32x4 mfma16(short8 a, short8 b, f32x4 c){
  return __builtin_amdgcn_mfma_f32_16x16x32_bf16(a,b,c,0,0,0);
}
static __device__ __forceinline__ short8 frag_of(uvec4 v){ return __builtin_bit_cast(short8, v); }

// 16B frag load from exchange buffer. Agent-scope relaxed atomic loads lower
// to global_load_dwordx2 sc1: bypass (possibly stale) L1/L2, read the LLC.
static __device__ __forceinline__ short8 ex_frag(const unsigned short* p){
  const unsigned long long* q = (const unsigned long long*)p;
  U8 u;
  u.q[0] = __hip_atomic_load(q,     __ATOMIC_RELAXED, __HIP_MEMORY_SCOPE_AGENT);
  u.q[1] = __hip_atomic_load(q + 1, __ATOMIC_RELAXED, __HIP_MEMORY_SCOPE_AGENT);
  return u.s;
}

// MFMA A-frag gather from chunked row-major exchange: lane (ln,quad) of tile
// `tile` reads rows tile*16+ln, k = kf*32+quad*8 .. +7.
// Chunk c = k>>4; element addr = (c*64 + tile*16 + ln)*16 + (k&15). 16B aligned.
static __device__ __forceinline__ short8 ex_fragA(const unsigned short* exbuf,
                                                  int tile, int ln, int quad, int kf){
  int k = kf*32 + quad*8;
  long off = ((long)((k>>4)*64 + tile*16 + ln))*16 + (k&15);
  return ex_frag(exbuf + off);
}

// u16 store with agent-scope coherence (write-through to LLC). Byte-granular
// write masks, single writer per halfword -> no RMW hazard.
static __device__ __forceinline__ void st16_sc1(unsigned short* p, unsigned short v){
  unsigned vv = v;
  asm volatile("global_store_short %0, %1, off sc1" :: "v"(p), "v"(vv) : "memory");
}

// Dense producer store into chunked row-major exchange: value at (row, col
// within chunk). Consecutive ln -> consecutive 2B -> 32B contiguous per quad.
static __device__ __forceinline__ void ex_store(unsigned short* exbuf, int chunk,
                                                int row, int col, float v){
  st16_sc1(exbuf + ((long)(chunk*64 + row))*16 + col, f2bf(v));
}

// mask A-frag built on the fly from int mask input (values are exactly 0/1).
static __device__ __forceinline__ short8 m_frag(const int* __restrict__ masks, long base, int col0){
  ivec4 a = *(const ivec4*)(masks + base + col0);
  ivec4 b = *(const ivec4*)(masks + base + col0 + 4);
  U8 t;
  t.u[0] = (a.x?0x3F80u:0u) | ((a.y?0x3F80u:0u)<<16);
  t.u[1] = (a.z?0x3F80u:0u) | ((a.w?0x3F80u:0u)<<16);
  t.u[2] = (b.x?0x3F80u:0u) | ((b.y?0x3F80u:0u)<<16);
  t.u[3] = (b.z?0x3F80u:0u) | ((b.w?0x3F80u:0u)<<16);
  return t.s;
}

// Group barrier, flag-based, fence-free.
// Producer: per-wave s_waitcnt vmcnt(0) drains all sc1 exchange stores to the
// LLC before s_barrier; after __syncthreads the whole block's data is at the
// LLC. Thread0 then publishes arrival with ONE plain sc1 store of the
// monotonic seq to this block's private slot (no atomic RMW chain).
// Consumer: wave0 polls all 32 slots with a single 32-lane sc1 load + __all
// (lanes >=32 mirror lanes 0-31), then __syncthreads releases the block.
static __device__ __forceinline__ void group_barrier(unsigned* flags, int r,
                                                     int w, int lane, unsigned seq){
  asm volatile("s_waitcnt vmcnt(0)" ::: "memory");
  __syncthreads();
  if (threadIdx.x == 0)
    __hip_atomic_store(flags + r, seq, __ATOMIC_RELAXED, __HIP_MEMORY_SCOPE_AGENT);
  if (w == 0){
    for (;;){
      unsigned v = __hip_atomic_load(flags + (lane & 31), __ATOMIC_RELAXED,
                                     __HIP_MEMORY_SCOPE_AGENT);
      if (__all(v >= seq)) break;
      __builtin_amdgcn_s_sleep(1);
    }
  }
  __syncthreads();
}

// ---------------------------------------------------------------------------
// Weight packing. B-frag layout (16x16x32): frag f holds B[n=lane&15][k = kf*32
// + (lane>>4)*8 + j], 16B/lane. Generic: rows of src tiled by 16 (tile*16+n).
// ---------------------------------------------------------------------------
__global__ void pack_generic(const float* __restrict__ src, uvec4* __restrict__ dst,
                             int KF, int srcK, int total){
  int t = blockIdx.x*256 + threadIdx.x;
  if (t >= total) return;
  int lane = t & 63, frag = t >> 6;
  int kf = frag % KF, tile = frag / KF;
  int n  = tile*16 + (lane & 15);
  int k0 = kf*32 + ((lane>>4)<<3);
  const float* s = src + (long)n*srcK + k0;
  U8 o;
  o.u[0] = (unsigned)f2bf(s[0]) | ((unsigned)f2bf(s[1])<<16);
  o.u[1] = (unsigned)f2bf(s[2]) | ((unsigned)f2bf(s[3])<<16);
  o.u[2] = (unsigned)f2bf(s[4]) | ((unsigned)f2bf(s[5])<<16);
  o.u[3] = (unsigned)f2bf(s[6]) | ((unsigned)f2bf(s[7])<<16);
  dst[t] = o.v;
}

// Gates blob: per role r (0..31), 4 n-tiles x 24 k-frags. Output col c=nt*16+n
// maps to (h_local=c>>2, gate=c&3), weight row R = gate*512 + r*16 + h_local.
// K order: [c_c 0..127 (W_ih), m 128..255 (W_ih), h_dec 0..511 (W_hh)].
__global__ void pack_gates(const float* __restrict__ Wih, const float* __restrict__ Whh,
                           uvec4* __restrict__ dst){
  int t = blockIdx.x*256 + threadIdx.x;
  if (t >= 3072*64) return;
  int lane = t & 63, frag = t >> 6;
  int kf = frag % 24; int rnt = frag / 24;
  int nt = rnt & 3; int r = rnt >> 2;
  int c = nt*16 + (lane & 15);
  int Rrow = (c & 3)*512 + r*16 + (c >> 2);
  int k = kf*32 + ((lane>>4)<<3);
  const float* s = (kf < 8) ? (Wih + (long)Rrow*256 + k)
                            : (Whh + (long)Rrow*512 + (k - 256));
  U8 o;
  o.u[0] = (unsigned)f2bf(s[0]) | ((unsigned)f2bf(s[1])<<16);
  o.u[1] = (unsigned)f2bf(s[2]) | ((unsigned)f2bf(s[3])<<16);
  o.u[2] = (unsigned)f2bf(s[4]) | ((unsigned)f2bf(s[5])<<16);
  o.u[3] = (unsigned)f2bf(s[6]) | ((unsigned)f2bf(s[7])<<16);
  dst[t] = o.v;
}

// ---------------------------------------------------------------------------
__global__ __launch_bounds__(512,2) void rits_main(
  const float* __restrict__ values, const int* __restrict__ masks, const float* __restrict__ deltas,
  const float* __restrict__ b_dh, const float* __restrict__ b_dx, const float* __restrict__ b_hr,
  const float* __restrict__ b_fr, const float* __restrict__ b_wc,
  const float* __restrict__ b_ih, const float* __restrict__ b_hh,
  const uvec4* __restrict__ BG, const uvec4* __restrict__ BDH, const uvec4* __restrict__ BHR,
  const uvec4* __restrict__ BDX, const uvec4* __restrict__ BFR, const uvec4* __restrict__ BWC,
  unsigned short* __restrict__ EX, unsigned* __restrict__ BAR,
  float* __restrict__ out)
{
  __shared__ __align__(16) uvec4 sh_whr[16*64];      // 16KB  W_hr tile frags
  __shared__ __align__(16) uvec4 sh_wwc[8*64];       // 8KB   W_wc tile frags
  __shared__ __align__(16) float sh_gbuf[64*68];     // 17KB  gates f32 (+x_h partials overlay)
  __shared__ __align__(16) float sh_za[4*1088];      // 17KB  z_h / alpha partials [kh*2+za][row*17+ln]

  const int tid = threadIdx.x;
  const int w = tid>>6, lane = tid&63, quad = lane>>4, ln = lane&15;
  const int g = blockIdx.x >> 5, r = blockIdx.x & 31, ft = r & 7, rep = r >> 3;

  const int mtp = w & 1, ntp = (w>>1) & 1, kh = w >> 2;  // P3 roles
  const int mtw = w & 3, khw = w >> 2;                   // P0/P1/P2 roles
  const bool isH = (w < 4);

  // ---- static weight registers
  uvec4 gB[24];
  #pragma unroll
  for (int ntL=0; ntL<2; ++ntL)
    #pragma unroll
    for (int kfL=0; kfL<12; ++kfL)
      gB[ntL*12+kfL] = BG[ (((long)(r*4 + (2*ntp+ntL))*24) + (12*kh+kfL))*64 + lane ];
  uvec4 pB[4];
  #pragma unroll
  for (int kf=0; kf<4; ++kf)
    pB[kf] = isH ? BDH[(r*4+kf)*64+lane] : BDX[(ft*4+kf)*64+lane];
  uvec4 fB[2];
  #pragma unroll
  for (int kk=0; kk<2; ++kk)
    fB[kk] = BFR[(ft*4 + 2*khw + kk)*64 + lane];

  for (int idx = tid; idx < 16*64; idx += 512) sh_whr[idx] = BHR[ft*16*64 + idx];
  for (int idx = tid; idx < 8*64;  idx += 512) sh_wwc[idx] = BWC[ft*8*64 + idx];

  const float bias_p  = isH ? b_dh[r*16+ln] : b_dx[ft*16+ln];
  const float bias_hr = b_hr[ft*16+ln];
  const float bias_fr = b_fr[ft*16+ln];
  const float bias_wc = b_wc[ft*16+ln];
  float gbias[2];
  #pragma unroll
  for (int ntL=0; ntL<2; ++ntL){
    int c = (2*ntp+ntL)*16 + ln;
    int Rr = (c&3)*512 + r*16 + (c>>2);
    gbias[ntL] = b_ih[Rr] + b_hh[Rr];
  }

  float hs[4] = {0,0,0,0}, cs[4] = {0,0,0,0};

  unsigned* flags = BAR + g*128;                           // 512B group stride
  unsigned seq = 0;

  unsigned short* const exb0 = EX + (long)g*57344;          // parity 0
  unsigned short* const exb1 = EX + (long)(8+g)*57344;      // parity 1

  const long rowA = (long)(g*64 + mtw*16 + ln);             // A-frag row (m = ln) for this wave

  __syncthreads();

  for (int t=0; t<256; ++t){
    unsigned short* const exh  = (t & 1) ? exb1 : exb0;     // h_dec  [32ck][64][16]
    unsigned short* const exxc = exh + 32768;               // x_c    [8ck][64][16]
    unsigned short* const exgx = exh + 40960;               // gamma_x[8ck][64][16]
    unsigned short* const excc = exh + 49152;               // c_c    [8ck][64][16]
    const long ibase = (rowA*256 + t)*128;                  // [B][T][F] element offset

    // ================= P0: gamma_h / h_dec (waves 0-3), gamma_x (waves 4-7)
    {
      short8 dA[4];
      #pragma unroll
      for (int kf=0; kf<4; ++kf){
        int c0 = kf*32 + quad*8;
        fvec4 lo = *(const fvec4*)(deltas + ibase + c0);
        fvec4 hi = *(const fvec4*)(deltas + ibase + c0 + 4);
        U8 p8;
        p8.u[0] = (unsigned)f2bf(lo.x) | ((unsigned)f2bf(lo.y)<<16);
        p8.u[1] = (unsigned)f2bf(lo.z) | ((unsigned)f2bf(lo.w)<<16);
        p8.u[2] = (unsigned)f2bf(hi.x) | ((unsigned)f2bf(hi.y)<<16);
        p8.u[3] = (unsigned)f2bf(hi.z) | ((unsigned)f2bf(hi.w)<<16);
        dA[kf] = p8.s;
      }
      f32x4 acc = {0.f,0.f,0.f,0.f};
      #pragma unroll
      for (int kf=0; kf<4; ++kf) acc = mfma16(dA[kf], frag_of(pB[kf]), acc);

      if (isH){
        #pragma unroll
        for (int i=0;i<4;++i){
          float gam = fexp2(-LOG2E * fmaxf(acc[i]+bias_p, 0.f));
          float hd  = hs[i]*gam;
          ex_store(exh, r, mtw*16 + quad*4 + i, ln, hd);
        }
      } else if (rep == 0){
        #pragma unroll
        for (int i=0;i<4;++i){
          float gx = fexp2(-LOG2E * fmaxf(acc[i]+bias_p, 0.f));
          ex_store(exgx, ft, mtw*16 + quad*4 + i, ln, gx);
        }
      }
    }
    group_barrier(flags, r, w, lane, ++seq);

    // ================= P1: x_h partials (all waves), then x_c (waves 0-3)
    {
      f32x4 axh = {0.f,0.f,0.f,0.f};
      #pragma unroll
      for (int kk2=0; kk2<8; ++kk2){
        int kf = 8*khw + kk2;
        short8 a = ex_fragA(exh, mtw, ln, quad, kf);
        axh = mfma16(a, frag_of(sh_whr[kf*64+lane]), axh);
      }
      #pragma unroll
      for (int i=0;i<4;++i)
        sh_gbuf[khw*1088 + (mtw*16+quad*4+i)*17 + ln] = axh[i];
    }
    __syncthreads();

    float xh_r[4], xx_r[4];
    int   m_r[4];
    if (isH){
      #pragma unroll
      for (int i=0;i<4;++i){
        int row = mtw*16 + quad*4 + i;
        float xh = sh_gbuf[row*17+ln] + sh_gbuf[1088 + row*17+ln] + bias_hr;
        long io = ((long)(g*64+row)*256 + t)*128 + ft*16 + ln;
        int   m  = masks[io];
        float xx = values[io];
        float xc = m ? xx : xh;
        xh_r[i]=xh; xx_r[i]=xx; m_r[i]=m;
        if (rep == 0)
          ex_store(exxc, ft, row, ln, xc);
      }
    }
    group_barrier(flags, r, w, lane, ++seq);

    // ================= P2: z_h & alpha partials, then c_h/c_c + output (waves 0-3)
    {
      f32x4 az = {0.f,0.f,0.f,0.f};
      #pragma unroll
      for (int kk2=0; kk2<2; ++kk2){
        int kf = 2*khw + kk2;
        short8 a = ex_fragA(exxc, mtw, ln, quad, kf);
        az = mfma16(a, frag_of(fB[kk2]), az);
      }
      f32x4 aa = {0.f,0.f,0.f,0.f};
      if (khw == 0){
        #pragma unroll
        for (int kk2=0; kk2<4; ++kk2){
          short8 a = ex_fragA(exgx, mtw, ln, quad, kk2);
          aa = mfma16(a, frag_of(sh_wwc[kk2*64+lane]), aa);
        }
      } else {
        #pragma unroll
        for (int kk2=0; kk2<4; ++kk2){
          short8 a = m_frag(masks, ibase, kk2*32 + quad*8);
          aa = mfma16(a, frag_of(sh_wwc[(4+kk2)*64+lane]), aa);
        }
      }
      #pragma unroll
      for (int i=0;i<4;++i){
        int row = mtw*16 + quad*4 + i;
        sh_za[(khw*2+0)*1088 + row*17 + ln] = az[i];
        sh_za[(khw*2+1)*1088 + row*17 + ln] = aa[i];
      }
    }
    __syncthreads();

    if (isH){
      #pragma unroll
      for (int i=0;i<4;++i){
        int row = mtw*16 + quad*4 + i;
        float zh = sh_za[row*17+ln] + sh_za[2*1088 + row*17+ln] + bias_fr;
        float al = sh_za[1088 + row*17+ln] + sh_za[3*1088 + row*17+ln] + bias_wc;
        float ch = al*zh + (1.f-al)*xh_r[i];
        float cc = m_r[i] ? xx_r[i] : ch;
        if (rep == 0){
          long oo = ((long)(g*64+row)*256 + t)*128 + ft*16 + ln;
          out[oo] = cc;
          ex_store(excc, ft, row, ln, cc);
        }
      }
    }
    group_barrier(flags, r, w, lane, ++seq);

    // ================= P3: gates GEMM ([c_c,m]@W_ih.T + h_dec@W_hh.T), LSTM update
    {
      f32x4 acc4[2][2];
      #pragma unroll
      for (int a=0;a<2;++a)
        #pragma unroll
        for (int b=0;b<2;++b){ acc4[a][b][0]=0.f; acc4[a][b][1]=0.f; acc4[a][b][2]=0.f; acc4[a][b][3]=0.f; }

      const long mb0 = ((long)(g*64 + (2*mtp+0)*16 + ln)*256 + t)*128;
      const long mb1 = mb0 + (long)16*256*128;

      if (kh == 0){
        #pragma unroll
        for (int kfL=0; kfL<12; ++kfL){
          short8 a0, a1;
          if (kfL < 4){
            a0 = ex_fragA(excc, 2*mtp+0, ln, quad, kfL);
            a1 = ex_fragA(excc, 2*mtp+1, ln, quad, kfL);
          } else if (kfL < 8){
            int c0 = (kfL-4)*32 + quad*8;
            a0 = m_frag(masks, mb0, c0);
            a1 = m_frag(masks, mb1, c0);
          } else {
            a0 = ex_fragA(exh, 2*mtp+0, ln, quad, kfL-8);
            a1 = ex_fragA(exh, 2*mtp+1, ln, quad, kfL-8);
          }
          acc4[0][0] = mfma16(a0, frag_of(gB[kfL]),    acc4[0][0]);
          acc4[0][1] = mfma16(a0, frag_of(gB[12+kfL]), acc4[0][1]);
          acc4[1][0] = mfma16(a1, frag_of(gB[kfL]),    acc4[1][0]);
          acc4[1][1] = mfma16(a1, frag_of(gB[12+kfL]), acc4[1][1]);
        }
      } else {
        #pragma unroll
        for (int kfL=0; kfL<12; ++kfL){
          int hk = 4 + kfL;
          short8 a0 = ex_fragA(exh, 2*mtp+0, ln, quad, hk);
          short8 a1 = ex_fragA(exh, 2*mtp+1, ln, quad, hk);
          acc4[0][0] = mfma16(a0, frag_of(gB[kfL]),    acc4[0][0]);
          acc4[0][1] = mfma16(a0, frag_of(gB[12+kfL]), acc4[0][1]);
          acc4[1][0] = mfma16(a1, frag_of(gB[kfL]),    acc4[1][0]);
          acc4[1][1] = mfma16(a1, frag_of(gB[12+kfL]), acc4[1][1]);
        }
      }

      if (kh == 0){
        #pragma unroll
        for (int mtL=0;mtL<2;++mtL)
          #pragma unroll
          for (int ntL=0;ntL<2;++ntL)
            #pragma unroll
            for (int i=0;i<4;++i){
              int row = (2*mtp+mtL)*16 + quad*4 + i;
              int col = (2*ntp+ntL)*16 + ln;
              sh_gbuf[row*68 + col] = acc4[mtL][ntL][i] + gbias[ntL];
            }
      }
      __syncthreads();
      if (kh == 1){
        #pragma unroll
        for (int mtL=0;mtL<2;++mtL)
          #pragma unroll
          for (int ntL=0;ntL<2;++ntL)
            #pragma unroll
            for (int i=0;i<4;++i){
              int row = (2*mtp+mtL)*16 + quad*4 + i;
              int col = (2*ntp+ntL)*16 + ln;
              sh_gbuf[row*68 + col] += acc4[mtL][ntL][i];
            }
      }
      __syncthreads();

      if (isH){
        #pragma unroll
        for (int i=0;i<4;++i){
          int row = mtw*16 + quad*4 + i;
          f32x4 gv = *(const f32x4*)&sh_gbuf[row*68 + 4*ln];
          float ig = sigm(gv[0]);
          float fg = sigm(gv[1]);
          float gg = tanh_(gv[2]);
          float og = sigm(gv[3]);
          cs[i] = fg*cs[i] + ig*gg;
          hs[i] = og*tanh_(cs[i]);
        }
      }
    }
    // no barrier: exchange buffers double-buffered by t-parity
  }
}

// ---------------------------------------------------------------------------
// Workspace layout (bytes)
#define OFF_G   0u
#define SZ_G    3145728u              // 32 roles x 4nt x 24kf x 1KB
#define OFF_DH  (OFF_G + SZ_G)
#define SZ_DH   131072u               // 32 x 4 x 1KB
#define OFF_HR  (OFF_DH + SZ_DH)
#define SZ_HR   131072u               // 8 x 16 x 1KB
#define OFF_DX  (OFF_HR + SZ_HR)
#define SZ_DX   32768u
#define OFF_FR  (OFF_DX + SZ_DX)
#define SZ_FR   32768u
#define OFF_WC  (OFF_FR + SZ_FR)
#define SZ_WC   65536u
#define OFF_EX  (OFF_WC + SZ_WC)
#define SZ_EX   1835008u              // 2 parity x 8 groups x 112KB
#define OFF_BAR (OFF_EX + SZ_EX)
#define SZ_BAR  4096u                 // 8 groups x 512B flag-array stride
#define WS_NEED (OFF_BAR + SZ_BAR)

extern "C" void kernel_launch(void* const* d_in, const int* in_sizes, int n_in,
                              void* d_out, int out_size, void* d_ws, size_t ws_size,
                              hipStream_t stream) {
  const float* values = (const float*)d_in[0];
  const int*   masks  = (const int*)  d_in[1];
  const float* deltas = (const float*)d_in[2];
  const float* W_dh = (const float*)d_in[3];  const float* b_dh = (const float*)d_in[4];
  const float* W_dx = (const float*)d_in[5];  const float* b_dx = (const float*)d_in[6];
  const float* W_hr = (const float*)d_in[7];  const float* b_hr = (const float*)d_in[8];
  const float* W_fr = (const float*)d_in[9];  const float* b_fr = (const float*)d_in[10];
  const float* W_wc = (const float*)d_in[11]; const float* b_wc = (const float*)d_in[12];
  const float* W_ih = (const float*)d_in[13]; const float* W_hh = (const float*)d_in[14];
  const float* b_ih = (const float*)d_in[15]; const float* b_hh = (const float*)d_in[16];

  if (ws_size < (size_t)WS_NEED) return;

  char* ws = (char*)d_ws;
  uvec4* BG  = (uvec4*)(ws + OFF_G);
  uvec4* BDH = (uvec4*)(ws + OFF_DH);
  uvec4* BHR = (uvec4*)(ws + OFF_HR);
  uvec4* BDX = (uvec4*)(ws + OFF_DX);
  uvec4* BFR = (uvec4*)(ws + OFF_FR);
  uvec4* BWC = (uvec4*)(ws + OFF_WC);
  unsigned short* EX = (unsigned short*)(ws + OFF_EX);
  unsigned* BAR = (unsigned*)(ws + OFF_BAR);

  pack_gates<<<768, 256, 0, stream>>>(W_ih, W_hh, BG);
  pack_generic<<<32, 256, 0, stream>>>(W_dh, BDH, 4, 128, 32*4*64);
  pack_generic<<<32, 256, 0, stream>>>(W_hr, BHR, 16, 512, 8*16*64);
  pack_generic<<<8, 256, 0, stream>>>(W_dx, BDX, 4, 128, 8*4*64);
  pack_generic<<<8, 256, 0, stream>>>(W_fr, BFR, 4, 128, 8*4*64);
  pack_generic<<<16, 256, 0, stream>>>(W_wc, BWC, 8, 256, 8*8*64);
  hipMemsetAsync(ws + OFF_BAR, 0, SZ_BAR, stream);

  rits_main<<<dim3(256), dim3(512), 0, stream>>>(
    values, masks, deltas,
    b_dh, b_dx, b_hr, b_fr, b_wc, b_ih, b_hh,
    BG, BDH, BHR, BDX, BFR, BWC,
    EX, BAR,
    (float*)d_out);
}

// Round 4
// 4033.636 us; speedup vs baseline: 1.9073x; 1.9073x over previous
//
#include <hip/hip_runtime.h>

// ---------------------------------------------------------------------------
// RITS recurrent scan, model-parallel persistent kernel, v3.1.
// 8 groups x 64 batch rows; each group = 32 blocks (1 per CU).
// Block (g, r): owns H-slice [16r,16r+16) and F-tile ft = r&7 (rep = r>>3).
//
// 4 waves / 256 threads per block. Wave w owns batch rows [g*64+w*16, +16)
// END-TO-END: every GEMM's full K is computed by one wave (x_h: 16 MFMAs over
// K=512; gates: 24 kf x 4 nt = 96 MFMAs with B-frags from LDS). NO intra-block
// reductions, NO __syncthreads inside phases -- only 3 group barriers/step.
//
// Gate n-tile remap (v3.1): gate = nt (not col&3), so lane (quad,ln) ends P3
// holding acc4[gate][i] for (row=quad*4+i, h_local=ln) -- the exact layout of
// hs[]/cs[]. No gate transpose, no sh_tr. LDS = 96KB gates + 16KB W_hr + 8KB
// W_wc = 120KB (within the 128KB envelope proven on gfx950), 1 block/CU.
//
// h_dec frags read in P1 are kept in VGPRs and reused in P3. Exchange =
// frag-major scatter stores + sc1 frag loads through the LLC (R1 layout,
// empirically lowest FETCH), double-buffered by t-parity. Barrier = per-block
// flag store + 32-lane poll (no atomic-RMW chain), proven in R2.
// ---------------------------------------------------------------------------

using short8 = __attribute__((ext_vector_type(8))) short;
using f32x4  = __attribute__((ext_vector_type(4))) float;
using fvec4  = __attribute__((ext_vector_type(4))) float;
using ivec4  = __attribute__((ext_vector_type(4))) int;
using uvec4  = __attribute__((ext_vector_type(4))) unsigned int;

#define LOG2E 1.4426950408889634f

union U8 {
  unsigned u[4];
  unsigned long long q[2];
  short8 s;
  uvec4 v;
};

static __device__ __forceinline__ unsigned short f2bf(float f){
  unsigned u = __builtin_bit_cast(unsigned, f);
  u += 0x7fffu + ((u>>16)&1u);
  return (unsigned short)(u>>16);
}
static __device__ __forceinline__ float fexp2(float x){ return __builtin_amdgcn_exp2f(x); }
static __device__ __forceinline__ float frcp(float x){ return __builtin_amdgcn_rcpf(x); }
static __device__ __forceinline__ float sigm(float x){ return frcp(1.f + fexp2(-LOG2E*x)); }
static __device__ __forceinline__ float tanh_(float x){
  x = fminf(fmaxf(x,-10.f),10.f);
  float e = fexp2(2.f*LOG2E*x);
  return (e-1.f)*frcp(e+1.f);
}
static __device__ __forceinline__ f32x4 mfma16(short8 a, short8 b, f32x4 c){
  return __builtin_amdgcn_mfma_f32_16x16x32_bf16(a,b,c,0,0,0);
}
static __device__ __forceinline__ short8 frag_of(uvec4 v){ return __builtin_bit_cast(short8, v); }

// 16B frag load from exchange buffer (agent-scope relaxed -> sc1, reads LLC).
static __device__ __forceinline__ short8 ex_frag(const unsigned short* p){
  const unsigned long long* q = (const unsigned long long*)p;
  U8 u;
  u.q[0] = __hip_atomic_load(q,     __ATOMIC_RELAXED, __HIP_MEMORY_SCOPE_AGENT);
  u.q[1] = __hip_atomic_load(q + 1, __ATOMIC_RELAXED, __HIP_MEMORY_SCOPE_AGENT);
  return u.s;
}

// u16 store with agent-scope coherence (write-through to LLC).
static __device__ __forceinline__ void st16_sc1(unsigned short* p, unsigned short v){
  unsigned vv = v;
  asm volatile("global_store_short %0, %1, off sc1" :: "v"(p), "v"(vv) : "memory");
}

// scatter one bf16 value at logical (row-in-tile rl, k-dim kk) into a
// 16x16x32 A-frag-major exchange region with KF k-frags, m-tile mt. (R1 layout)
static __device__ __forceinline__ void scatter_ex(unsigned short* exbuf, int mt, int KF,
                                                  int rl, int kk, float val){
  int kf = kk>>5, ko = kk&31;
  int L = rl + 16*(ko>>3);
  long off = ((long)(mt*KF+kf)*64 + L)*8 + (ko&7);
  st16_sc1(exbuf + off, f2bf(val));
}

// mask A-frag built from two ivec4 register values (mask values exactly 0/1).
static __device__ __forceinline__ short8 mi_frag(ivec4 a, ivec4 b){
  U8 t;
  t.u[0] = (a.x?0x3F80u:0u) | ((a.y?0x3F80u:0u)<<16);
  t.u[1] = (a.z?0x3F80u:0u) | ((a.w?0x3F80u:0u)<<16);
  t.u[2] = (b.x?0x3F80u:0u) | ((b.y?0x3F80u:0u)<<16);
  t.u[3] = (b.z?0x3F80u:0u) | ((b.w?0x3F80u:0u)<<16);
  return t.s;
}

// Group barrier, flag-based, fence-free (proven in R2). Producer: per-wave
// vmcnt(0) drains all sc1 exchange stores to the LLC; after __syncthreads the
// whole block's data is at the LLC; thread0 publishes arrival with one plain
// sc1 store of the monotonic seq. Consumer: wave0 polls all 32 flags with one
// 32-lane sc1 load + __all, then __syncthreads releases the block.
static __device__ __forceinline__ void group_barrier(unsigned* flags, int r,
                                                     int w, int lane, unsigned seq){
  asm volatile("s_waitcnt vmcnt(0)" ::: "memory");
  __syncthreads();
  if (threadIdx.x == 0)
    __hip_atomic_store(flags + r, seq, __ATOMIC_RELAXED, __HIP_MEMORY_SCOPE_AGENT);
  if (w == 0){
    for (;;){
      unsigned v = __hip_atomic_load(flags + (lane & 31), __ATOMIC_RELAXED,
                                     __HIP_MEMORY_SCOPE_AGENT);
      if (__all(v >= seq)) break;
      __builtin_amdgcn_s_sleep(1);
    }
  }
  __syncthreads();
}

// ---------------------------------------------------------------------------
// Weight packing. B-frag layout (16x16x32): frag f holds B[n=lane&15][k = kf*32
// + (lane>>4)*8 + j], 16B/lane. Generic: rows of src tiled by 16 (tile*16+n).
// ---------------------------------------------------------------------------
__global__ void pack_generic(const float* __restrict__ src, uvec4* __restrict__ dst,
                             int KF, int srcK, int total){
  int t = blockIdx.x*256 + threadIdx.x;
  if (t >= total) return;
  int lane = t & 63, frag = t >> 6;
  int kf = frag % KF, tile = frag / KF;
  int n  = tile*16 + (lane & 15);
  int k0 = kf*32 + ((lane>>4)<<3);
  const float* s = src + (long)n*srcK + k0;
  U8 o;
  o.u[0] = (unsigned)f2bf(s[0]) | ((unsigned)f2bf(s[1])<<16);
  o.u[1] = (unsigned)f2bf(s[2]) | ((unsigned)f2bf(s[3])<<16);
  o.u[2] = (unsigned)f2bf(s[4]) | ((unsigned)f2bf(s[5])<<16);
  o.u[3] = (unsigned)f2bf(s[6]) | ((unsigned)f2bf(s[7])<<16);
  dst[t] = o.v;
}

// Gates blob: per role r (0..31), 4 n-tiles x 24 k-frags. v3.1 mapping:
// n-tile = GATE (i,f,g,o), column within tile = h_local. Output col c=nt*16+n
// -> weight row R = nt*512 + r*16 + n. So lane (quad,ln)'s accumulator
// acc4[nt][i] is gate nt for (row=quad*4+i, h=r*16+ln) -- no transpose needed.
// K order: [c_c 0..127 (W_ih), m 128..255 (W_ih), h_dec 0..511 (W_hh)].
__global__ void pack_gates(const float* __restrict__ Wih, const float* __restrict__ Whh,
                           uvec4* __restrict__ dst){
  int t = blockIdx.x*256 + threadIdx.x;
  if (t >= 3072*64) return;
  int lane = t & 63, frag = t >> 6;
  int kf = frag % 24; int rnt = frag / 24;
  int nt = rnt & 3; int r = rnt >> 2;
  int Rrow = nt*512 + r*16 + (lane & 15);
  int k = kf*32 + ((lane>>4)<<3);
  const float* s = (kf < 8) ? (Wih + (long)Rrow*256 + k)
                            : (Whh + (long)Rrow*512 + (k - 256));
  U8 o;
  o.u[0] = (unsigned)f2bf(s[0]) | ((unsigned)f2bf(s[1])<<16);
  o.u[1] = (unsigned)f2bf(s[2]) | ((unsigned)f2bf(s[3])<<16);
  o.u[2] = (unsigned)f2bf(s[4]) | ((unsigned)f2bf(s[5])<<16);
  o.u[3] = (unsigned)f2bf(s[6]) | ((unsigned)f2bf(s[7])<<16);
  dst[t] = o.v;
}

// ---------------------------------------------------------------------------
__global__ __launch_bounds__(256,1) void rits_main(
  const float* __restrict__ values, const int* __restrict__ masks, const float* __restrict__ deltas,
  const float* __restrict__ b_dh, const float* __restrict__ b_dx, const float* __restrict__ b_hr,
  const float* __restrict__ b_fr, const float* __restrict__ b_wc,
  const float* __restrict__ b_ih, const float* __restrict__ b_hh,
  const uvec4* __restrict__ BG, const uvec4* __restrict__ BDH, const uvec4* __restrict__ BHR,
  const uvec4* __restrict__ BDX, const uvec4* __restrict__ BFR, const uvec4* __restrict__ BWC,
  unsigned short* __restrict__ EX, unsigned* __restrict__ BAR,
  float* __restrict__ out)
{
  __shared__ __align__(16) uvec4 sh_g[96*64];        // 96KB gates B-frags [nt*24+kf][lane]
  __shared__ __align__(16) uvec4 sh_whr[16*64];      // 16KB W_hr tile frags
  __shared__ __align__(16) uvec4 sh_wwc[8*64];       //  8KB W_wc tile frags
                                                     // total 120KB, 1 block/CU

  const int tid = threadIdx.x;
  const int w = tid>>6, lane = tid&63, quad = lane>>4, ln = lane&15;
  const int g = blockIdx.x >> 5, r = blockIdx.x & 31, ft = r & 7, rep = r >> 3;

  // ---- static weights: LDS blobs
  for (int idx = tid; idx < 96*64; idx += 256) sh_g[idx]   = BG[(long)r*6144 + idx];
  for (int idx = tid; idx < 16*64; idx += 256) sh_whr[idx] = BHR[ft*1024 + idx];
  for (int idx = tid; idx < 8*64;  idx += 256) sh_wwc[idx] = BWC[ft*512 + idx];

  // ---- static weights: registers
  uvec4 pB[8];                                   // dh kf0..3, dx kf0..3
  #pragma unroll
  for (int kf=0; kf<4; ++kf){
    pB[kf]   = BDH[(r*4+kf)*64+lane];
    pB[4+kf] = BDX[(ft*4+kf)*64+lane];
  }
  uvec4 fB[4];
  #pragma unroll
  for (int kf=0; kf<4; ++kf) fB[kf] = BFR[(ft*4+kf)*64+lane];

  const float bias_dh = b_dh[r*16+ln];
  const float bias_dx = b_dx[ft*16+ln];
  const float bias_hr = b_hr[ft*16+ln];
  const float bias_fr = b_fr[ft*16+ln];
  const float bias_wc = b_wc[ft*16+ln];
  float gbias[4];
  #pragma unroll
  for (int nt=0; nt<4; ++nt){
    int Rr = nt*512 + r*16 + ln;                 // gate=nt, h_local=ln
    gbias[nt] = b_ih[Rr] + b_hh[Rr];
  }

  float hs[4] = {0,0,0,0}, cs[4] = {0,0,0,0};

  unsigned* flags = BAR + g*128;                           // 512B group stride
  unsigned seq = 0;

  unsigned short* const exb0 = EX + (long)g*57344;          // parity 0
  unsigned short* const exb1 = EX + (long)(8+g)*57344;      // parity 1

  const long rowA = (long)(g*64 + w*16 + ln);               // A-frag row (m=ln)

  __syncthreads();

  for (int t=0; t<256; ++t){
    unsigned short* const exh  = (t & 1) ? exb1 : exb0;     // h_dec  [4mt][16kf]
    unsigned short* const exxc = exh + 32768;               // x_c    [4mt][4kf]
    unsigned short* const exgx = exh + 40960;               // gamma_x[4mt][4kf]
    unsigned short* const excc = exh + 49152;               // c_c    [4mt][4kf]
    const long ibase = (rowA*256 + t)*128;                  // [B][T][F] elem offset

    // ---- step-top prefetch: scalar masks/values for P1/P2 epilogues,
    //      mask A-frags for P2/P3 (all plain cached loads)
    long io[4]; int mm[4]; float vv[4];
    #pragma unroll
    for (int i=0;i<4;++i){
      io[i] = ((long)(g*64 + w*16 + quad*4 + i)*256 + t)*128 + ft*16 + ln;
      mm[i] = masks[io[i]];
      vv[i] = values[io[i]];
    }
    short8 mA[4];
    #pragma unroll
    for (int kf=0; kf<4; ++kf){
      int c0 = kf*32 + quad*8;
      ivec4 a = *(const ivec4*)(masks + ibase + c0);
      ivec4 b = *(const ivec4*)(masks + ibase + c0 + 4);
      mA[kf] = mi_frag(a, b);
    }

    // ================= P0: gamma_h / h_dec (all waves), gamma_x (rep0)
    {
      short8 dA[4];
      #pragma unroll
      for (int kf=0; kf<4; ++kf){
        int c0 = kf*32 + quad*8;
        fvec4 lo = *(const fvec4*)(deltas + ibase + c0);
        fvec4 hi = *(const fvec4*)(deltas + ibase + c0 + 4);
        U8 p8;
        p8.u[0] = (unsigned)f2bf(lo.x) | ((unsigned)f2bf(lo.y)<<16);
        p8.u[1] = (unsigned)f2bf(lo.z) | ((unsigned)f2bf(lo.w)<<16);
        p8.u[2] = (unsigned)f2bf(hi.x) | ((unsigned)f2bf(hi.y)<<16);
        p8.u[3] = (unsigned)f2bf(hi.z) | ((unsigned)f2bf(hi.w)<<16);
        dA[kf] = p8.s;
      }
      f32x4 ah = {0.f,0.f,0.f,0.f};
      #pragma unroll
      for (int kf=0; kf<4; ++kf) ah = mfma16(dA[kf], frag_of(pB[kf]), ah);
      #pragma unroll
      for (int i=0;i<4;++i){
        float gam = fexp2(-LOG2E * fmaxf(ah[i]+bias_dh, 0.f));
        float hd  = hs[i]*gam;
        scatter_ex(exh, w, 16, quad*4+i, r*16+ln, hd);
      }
      if (rep == 0){
        f32x4 ax = {0.f,0.f,0.f,0.f};
        #pragma unroll
        for (int kf=0; kf<4; ++kf) ax = mfma16(dA[kf], frag_of(pB[4+kf]), ax);
        #pragma unroll
        for (int i=0;i<4;++i){
          float gx = fexp2(-LOG2E * fmaxf(ax[i]+bias_dx, 0.f));
          scatter_ex(exgx, w, 4, quad*4+i, ft*16+ln, gx);
        }
      }
    }
    group_barrier(flags, r, w, lane, ++seq);

    // ================= P1: x_h (full K=512, one wave), x_c store
    short8 hA[16];                               // kept live for P3 reuse
    float xh_r[4];
    {
      #pragma unroll
      for (int kf=0; kf<16; ++kf)
        hA[kf] = ex_frag(exh + ((long)(w*16+kf)*64 + lane)*8);
      f32x4 axh = {0.f,0.f,0.f,0.f};
      #pragma unroll
      for (int kf=0; kf<16; ++kf)
        axh = mfma16(hA[kf], frag_of(sh_whr[kf*64+lane]), axh);
      #pragma unroll
      for (int i=0;i<4;++i){
        float xh = axh[i] + bias_hr;
        xh_r[i] = xh;
        if (rep == 0){
          float xc = mm[i] ? vv[i] : xh;
          scatter_ex(exxc, w, 4, quad*4+i, ft*16+ln, xc);
        }
      }
    }
    group_barrier(flags, r, w, lane, ++seq);

    // ================= P2: z_h & alpha (full K, one wave), c_c + output
    {
      f32x4 az = {0.f,0.f,0.f,0.f};
      #pragma unroll
      for (int kf=0; kf<4; ++kf){
        short8 a = ex_frag(exxc + ((long)(w*4+kf)*64 + lane)*8);
        az = mfma16(a, frag_of(fB[kf]), az);
      }
      f32x4 aa = {0.f,0.f,0.f,0.f};
      #pragma unroll
      for (int kf=0; kf<4; ++kf){
        short8 a = ex_frag(exgx + ((long)(w*4+kf)*64 + lane)*8);
        aa = mfma16(a, frag_of(sh_wwc[kf*64+lane]), aa);
      }
      #pragma unroll
      for (int kf=0; kf<4; ++kf)
        aa = mfma16(mA[kf], frag_of(sh_wwc[(4+kf)*64+lane]), aa);
      #pragma unroll
      for (int i=0;i<4;++i){
        float zh = az[i] + bias_fr;
        float al = aa[i] + bias_wc;
        float ch = al*zh + (1.f-al)*xh_r[i];
        float cc = mm[i] ? vv[i] : ch;
        if (rep == 0){
          out[io[i]] = cc;
          scatter_ex(excc, w, 4, quad*4+i, ft*16+ln, cc);
        }
      }
    }
    group_barrier(flags, r, w, lane, ++seq);

    // ================= P3: gates GEMM (24 kf x 4 nt, one wave), LSTM update
    {
      f32x4 acc4[4];
      #pragma unroll
      for (int nt=0; nt<4; ++nt){ acc4[nt][0]=0.f; acc4[nt][1]=0.f; acc4[nt][2]=0.f; acc4[nt][3]=0.f; }

      #pragma unroll
      for (int kf=0; kf<4; ++kf){                 // c_c (exchange)
        short8 a = ex_frag(excc + ((long)(w*4+kf)*64 + lane)*8);
        #pragma unroll
        for (int nt=0; nt<4; ++nt)
          acc4[nt] = mfma16(a, frag_of(sh_g[(nt*24+kf)*64+lane]), acc4[nt]);
      }
      #pragma unroll
      for (int kf=0; kf<4; ++kf){                 // m (registers)
        #pragma unroll
        for (int nt=0; nt<4; ++nt)
          acc4[nt] = mfma16(mA[kf], frag_of(sh_g[(nt*24+4+kf)*64+lane]), acc4[nt]);
      }
      #pragma unroll
      for (int kf=0; kf<16; ++kf){                // h_dec (reused VGPR frags)
        #pragma unroll
        for (int nt=0; nt<4; ++nt)
          acc4[nt] = mfma16(hA[kf], frag_of(sh_g[(nt*24+8+kf)*64+lane]), acc4[nt]);
      }

      // acc4[gate][i] is already per-lane (row=quad*4+i, h=ln): no transpose.
      #pragma unroll
      for (int i=0;i<4;++i){
        float ig = sigm(acc4[0][i] + gbias[0]);
        float fg = sigm(acc4[1][i] + gbias[1]);
        float gg = tanh_(acc4[2][i] + gbias[2]);
        float og = sigm(acc4[3][i] + gbias[3]);
        cs[i] = fg*cs[i] + ig*gg;
        hs[i] = og*tanh_(cs[i]);
      }
    }
    // no barrier: exchange buffers double-buffered by t-parity
  }
}

// ---------------------------------------------------------------------------
// Workspace layout (bytes)
#define OFF_G   0u
#define SZ_G    3145728u              // 32 roles x 4nt x 24kf x 1KB
#define OFF_DH  (OFF_G + SZ_G)
#define SZ_DH   131072u               // 32 x 4 x 1KB
#define OFF_HR  (OFF_DH + SZ_DH)
#define SZ_HR   131072u               // 8 x 16 x 1KB
#define OFF_DX  (OFF_HR + SZ_HR)
#define SZ_DX   32768u
#define OFF_FR  (OFF_DX + SZ_DX)
#define SZ_FR   32768u
#define OFF_WC  (OFF_FR + SZ_FR)
#define SZ_WC   65536u
#define OFF_EX  (OFF_WC + SZ_WC)
#define SZ_EX   1835008u              // 2 parity x 8 groups x 112KB
#define OFF_BAR (OFF_EX + SZ_EX)
#define SZ_BAR  4096u                 // 8 groups x 512B flag-array stride
#define WS_NEED (OFF_BAR + SZ_BAR)

extern "C" void kernel_launch(void* const* d_in, const int* in_sizes, int n_in,
                              void* d_out, int out_size, void* d_ws, size_t ws_size,
                              hipStream_t stream) {
  const float* values = (const float*)d_in[0];
  const int*   masks  = (const int*)  d_in[1];
  const float* deltas = (const float*)d_in[2];
  const float* W_dh = (const float*)d_in[3];  const float* b_dh = (const float*)d_in[4];
  const float* W_dx = (const float*)d_in[5];  const float* b_dx = (const float*)d_in[6];
  const float* W_hr = (const float*)d_in[7];  const float* b_hr = (const float*)d_in[8];
  const float* W_fr = (const float*)d_in[9];  const float* b_fr = (const float*)d_in[10];
  const float* W_wc = (const float*)d_in[11]; const float* b_wc = (const float*)d_in[12];
  const float* W_ih = (const float*)d_in[13]; const float* W_hh = (const float*)d_in[14];
  const float* b_ih = (const float*)d_in[15]; const float* b_hh = (const float*)d_in[16];

  if (ws_size < (size_t)WS_NEED) return;

  char* ws = (char*)d_ws;
  uvec4* BG  = (uvec4*)(ws + OFF_G);
  uvec4* BDH = (uvec4*)(ws + OFF_DH);
  uvec4* BHR = (uvec4*)(ws + OFF_HR);
  uvec4* BDX = (uvec4*)(ws + OFF_DX);
  uvec4* BFR = (uvec4*)(ws + OFF_FR);
  uvec4* BWC = (uvec4*)(ws + OFF_WC);
  unsigned short* EX = (unsigned short*)(ws + OFF_EX);
  unsigned* BAR = (unsigned*)(ws + OFF_BAR);

  pack_gates<<<768, 256, 0, stream>>>(W_ih, W_hh, BG);
  pack_generic<<<32, 256, 0, stream>>>(W_dh, BDH, 4, 128, 32*4*64);
  pack_generic<<<32, 256, 0, stream>>>(W_hr, BHR, 16, 512, 8*16*64);
  pack_generic<<<8, 256, 0, stream>>>(W_dx, BDX, 4, 128, 8*4*64);
  pack_generic<<<8, 256, 0, stream>>>(W_fr, BFR, 4, 128, 8*4*64);
  pack_generic<<<16, 256, 0, stream>>>(W_wc, BWC, 8, 256, 8*8*64);
  hipMemsetAsync(ws + OFF_BAR, 0, SZ_BAR, stream);

  rits_main<<<dim3(256), dim3(256), 0, stream>>>(
    values, masks, deltas,
    b_dh, b_dx, b_hr, b_fr, b_wc, b_ih, b_hh,
    BG, BDH, BHR, BDX, BFR, BWC,
    EX, BAR,
    (float*)d_out);
}